// Round 1
// baseline (292.371 us; speedup 1.0000x reference)
//
#include <hip/hip_runtime.h>

#define IMG_H 1024
#define IMG_W 1024
#define RPB   32      // output rows per block
#define TPB   256     // threads per block; each thread owns 4 columns

__device__ __forceinline__ void hsum_row(const float* __restrict__ xr,
                                         const float* __restrict__ yr,
                                         int c,
                                         float* hx, float* hy,
                                         float* hxx, float* hyy, float* hxy)
{
    // columns c..c+3 output; need inputs c-1..c+4 (zero pad at image edges)
    float4 xv = *reinterpret_cast<const float4*>(xr + c);
    float4 yv = *reinterpret_cast<const float4*>(yr + c);
    float xs[6], ys[6];
    xs[0] = (c > 0) ? xr[c - 1] : 0.0f;
    ys[0] = (c > 0) ? yr[c - 1] : 0.0f;
    xs[1] = xv.x; xs[2] = xv.y; xs[3] = xv.z; xs[4] = xv.w;
    ys[1] = yv.x; ys[2] = yv.y; ys[3] = yv.z; ys[4] = yv.w;
    xs[5] = (c + 4 < IMG_W) ? xr[c + 4] : 0.0f;
    ys[5] = (c + 4 < IMG_W) ? yr[c + 4] : 0.0f;

    float pxx[6], pyy[6], pxy[6];
#pragma unroll
    for (int k = 0; k < 6; ++k) {
        pxx[k] = xs[k] * xs[k];
        pyy[k] = ys[k] * ys[k];
        pxy[k] = xs[k] * ys[k];
    }
#pragma unroll
    for (int j = 0; j < 4; ++j) {
        hx[j]  = xs[j]  + xs[j + 1]  + xs[j + 2];
        hy[j]  = ys[j]  + ys[j + 1]  + ys[j + 2];
        hxx[j] = pxx[j] + pxx[j + 1] + pxx[j + 2];
        hyy[j] = pyy[j] + pyy[j + 1] + pyy[j + 2];
        hxy[j] = pxy[j] + pxy[j + 1] + pxy[j + 2];
    }
}

__global__ __launch_bounds__(TPB)
void ssim_map_sum_kernel(const float* __restrict__ x,
                         const float* __restrict__ y,
                         float* __restrict__ ws_sum)
{
    const int rb = blockIdx.x;          // row-block within image
    const int n  = blockIdx.y;          // image index
    const int r0 = rb * RPB;
    const int c  = (int)threadIdx.x * 4;

    const float* xi = x + (size_t)n * IMG_H * IMG_W;
    const float* yi = y + (size_t)n * IMG_H * IMG_W;

    const float C1   = 0.01f * 0.01f;
    const float C2   = 0.03f * 0.03f;
    const float EPSv = 1e-8f;
    const float inv9 = 1.0f / 9.0f;

    float hAx[4], hAy[4], hAxx[4], hAyy[4], hAxy[4];
    float hBx[4], hBy[4], hBxx[4], hByy[4], hBxy[4];
    float hCx[4], hCy[4], hCxx[4], hCyy[4], hCxy[4];

    if (r0 > 0) {
        hsum_row(xi + (size_t)(r0 - 1) * IMG_W, yi + (size_t)(r0 - 1) * IMG_W,
                 c, hAx, hAy, hAxx, hAyy, hAxy);
    } else {
#pragma unroll
        for (int j = 0; j < 4; ++j) { hAx[j]=0.f; hAy[j]=0.f; hAxx[j]=0.f; hAyy[j]=0.f; hAxy[j]=0.f; }
    }
    hsum_row(xi + (size_t)r0 * IMG_W, yi + (size_t)r0 * IMG_W,
             c, hBx, hBy, hBxx, hByy, hBxy);

    float acc = 0.0f;

    for (int i = 0; i < RPB; ++i) {
        const int r = r0 + i;
        if (r + 1 < IMG_H) {
            hsum_row(xi + (size_t)(r + 1) * IMG_W, yi + (size_t)(r + 1) * IMG_W,
                     c, hCx, hCy, hCxx, hCyy, hCxy);
        } else {
#pragma unroll
            for (int j = 0; j < 4; ++j) { hCx[j]=0.f; hCy[j]=0.f; hCxx[j]=0.f; hCyy[j]=0.f; hCxy[j]=0.f; }
        }

#pragma unroll
        for (int j = 0; j < 4; ++j) {
            const float sx  = hAx[j]  + hBx[j]  + hCx[j];
            const float sy  = hAy[j]  + hBy[j]  + hCy[j];
            const float sxx = hAxx[j] + hBxx[j] + hCxx[j];
            const float syy = hAyy[j] + hByy[j] + hCyy[j];
            const float sxy = hAxy[j] + hBxy[j] + hCxy[j];

            const float mu_x = sx * inv9;
            const float mu_y = sy * inv9;
            const float mxx  = mu_x * mu_x;
            const float myy  = mu_y * mu_y;
            const float mxy  = mu_x * mu_y;
            const float sigx  = sxx * inv9 - mxx;
            const float sigy  = syy * inv9 - myy;
            const float sigxy = sxy * inv9 - mxy;

            const float num = (2.0f * mxy + C1) * (2.0f * sigxy + C2);
            const float den = (mxx + myy + C1) * (sigx + sigy + C2) + EPSv;
            acc += num / den;
        }

        // shift ring: A <- B, B <- C
#pragma unroll
        for (int j = 0; j < 4; ++j) {
            hAx[j]=hBx[j]; hAy[j]=hBy[j]; hAxx[j]=hBxx[j]; hAyy[j]=hByy[j]; hAxy[j]=hBxy[j];
            hBx[j]=hCx[j]; hBy[j]=hCy[j]; hBxx[j]=hCxx[j]; hByy[j]=hCyy[j]; hBxy[j]=hCxy[j];
        }
    }

    // wave (64-lane) reduction
#pragma unroll
    for (int off = 32; off > 0; off >>= 1)
        acc += __shfl_down(acc, off);

    __shared__ float red[TPB / 64];
    const int lane = (int)threadIdx.x & 63;
    const int wave = (int)threadIdx.x >> 6;
    if (lane == 0) red[wave] = acc;
    __syncthreads();
    if (threadIdx.x == 0) {
        float s = 0.0f;
#pragma unroll
        for (int w = 0; w < TPB / 64; ++w) s += red[w];
        atomicAdd(ws_sum, s);
    }
}

__global__ void ssim_finalize_kernel(const float* __restrict__ ws_sum,
                                     float* __restrict__ out,
                                     float inv_count)
{
    out[0] = 1.0f - ws_sum[0] * inv_count;
}

extern "C" void kernel_launch(void* const* d_in, const int* in_sizes, int n_in,
                              void* d_out, int out_size, void* d_ws, size_t ws_size,
                              hipStream_t stream)
{
    const float* x = (const float*)d_in[0];
    const float* y = (const float*)d_in[1];
    float* out  = (float*)d_out;
    float* wsum = (float*)d_ws;

    const long long total = (long long)in_sizes[0];       // 32*1024*1024
    const int N = (int)(total / ((long long)IMG_H * IMG_W));

    hipMemsetAsync(wsum, 0, sizeof(float), stream);

    dim3 grid(IMG_H / RPB, N);
    ssim_map_sum_kernel<<<grid, TPB, 0, stream>>>(x, y, wsum);

    ssim_finalize_kernel<<<1, 1, 0, stream>>>(wsum, out, 1.0f / (float)total);
}